// Round 2
// baseline (297.846 us; speedup 1.0000x reference)
//
#include <hip/hip_runtime.h>

// ---------------- types / helpers ----------------
typedef __attribute__((ext_vector_type(8))) short bf16x8;   // 8 x bf16 = 4 VGPR
typedef __attribute__((ext_vector_type(4))) float f32x4;

__device__ __forceinline__ unsigned short f2bf(float f) {
    union { float f; unsigned u; } v; v.f = f;
    unsigned r = v.u + 0x7fffu + ((v.u >> 16) & 1u);   // RNE
    return (unsigned short)(r >> 16);
}

// ---------------- problem constants ----------------
#define BATCH   2048
#define DIM     128     // in_main
#define CDIM    64      // embedding out
#define TSTEPS  300
#define NCHUNK  5       // 5 * 64 = 320 padded t-rows
#define KPAD    128     // padded hidden dim (100 -> 128)

// workspace layout (bytes)
#define WT_OFF  0            // 3 * 128*128 bf16 = 98304  (U2^T, U3^T, U4^T padded)
#define CB_OFF  98304        // 3 * 128 f32 = 1536        (c2,c3,c4 padded)
#define G_OFF   99840        // 2048*128 f32 = 1 MiB
#define E_OFF   1148416      // 2048*128 f32 = 1 MiB

// main-kernel LDS layout (bytes)
#define OFF_W   0            // 3 * 32768 swizzled bf16 weights
#define OFF_A   98304        // 2 * (64*128) bf16 activation buffers
#define OFF_X   131072       // 128 f32
#define OFF_G   131584
#define OFF_E   132096
#define OFF_C2  132608
#define OFF_C3  133120
#define OFF_C4  133632
#define OFF_P   134144       // 32 f32 partials
#define SMEM_SZ 134272

// ---------------- prep: pack/pad/transpose integrand weights to bf16 ----------------
__global__ __launch_bounds__(256) void prep_kernel(
    const float* __restrict__ U2, const float* __restrict__ c2,
    const float* __restrict__ U3, const float* __restrict__ c3,
    const float* __restrict__ U4, const float* __restrict__ c4,
    unsigned char* __restrict__ ws)
{
    int idx = blockIdx.x * 256 + threadIdx.x;          // grid = 48 blocks
    for (int i = idx; i < 3 * 128 * 128; i += 48 * 256) {
        int m = i >> 14;          // which matrix
        int r = i & 16383;
        int n = r >> 7;           // out-neuron (row of W^T)
        int k = r & 127;          // in-neuron
        float v;
        if (m == 0)      v = (n < 100 && k < 100) ? U2[k * 100 + n] : 0.f;
        else if (m == 1) v = (n < 100 && k < 100) ? U3[k * 100 + n] : 0.f;
        else             v = (k < 100) ? U4[k * 128 + n] : 0.f;   // U4: 100 x 128
        *(unsigned short*)(ws + WT_OFF + m * 32768 + n * 256 + k * 2) = f2bf(v);
    }
    if (idx < 384) {   // padded biases, f32
        int m = idx >> 7, j = idx & 127;
        float v;
        if (m == 0)      v = (j < 100) ? c2[j] : 0.f;
        else if (m == 1) v = (j < 100) ? c3[j] : 0.f;
        else             v = c4[j];
        *(float*)(ws + CB_OFF + idx * 4) = v;
    }
}

// ---------------- embedding net + per-row g,e precompute ----------------
// g = x @ U1[0:128,:]        (t-scaled part)
// e = h @ U1[128:192,:] + c1 (t-independent part),  both padded 100->128 with zeros
__global__ __launch_bounds__(256) void embed_kernel(
    const float* __restrict__ x,
    const float* __restrict__ W1, const float* __restrict__ b1,
    const float* __restrict__ W2, const float* __restrict__ b2,
    const float* __restrict__ W3, const float* __restrict__ b3,
    const float* __restrict__ U1, const float* __restrict__ c1,
    float* __restrict__ g_out, float* __restrict__ e_out)
{
    __shared__ float xs[8][128];
    __shared__ float h1[8][200];
    __shared__ float h2[8][200];
    __shared__ float h3[8][64];
    const int tid = threadIdx.x;
    const int b0 = blockIdx.x * 8;

    for (int i = tid; i < 8 * 128; i += 256) {
        int r = i >> 7, d = i & 127;
        xs[r][d] = x[(b0 + r) * 128 + d];
    }
    __syncthreads();

    const int j = tid;
    if (j < 200) {
        float acc[8];
#pragma unroll
        for (int r = 0; r < 8; ++r) acc[r] = b1[j];
        for (int d = 0; d < 128; ++d) {
            float w = W1[d * 200 + j];
#pragma unroll
            for (int r = 0; r < 8; ++r) acc[r] += xs[r][d] * w;
        }
#pragma unroll
        for (int r = 0; r < 8; ++r) h1[r][j] = fmaxf(acc[r], 0.f);
    }
    __syncthreads();
    if (j < 200) {
        float acc[8];
#pragma unroll
        for (int r = 0; r < 8; ++r) acc[r] = b2[j];
        for (int d = 0; d < 200; ++d) {
            float w = W2[d * 200 + j];
#pragma unroll
            for (int r = 0; r < 8; ++r) acc[r] += h1[r][d] * w;
        }
#pragma unroll
        for (int r = 0; r < 8; ++r) h2[r][j] = fmaxf(acc[r], 0.f);
    }
    __syncthreads();
    if (j < 64) {
        float acc[8];
#pragma unroll
        for (int r = 0; r < 8; ++r) acc[r] = b3[j];
        for (int d = 0; d < 200; ++d) {
            float w = W3[d * 64 + j];
#pragma unroll
            for (int r = 0; r < 8; ++r) acc[r] += h2[r][d] * w;
        }
#pragma unroll
        for (int r = 0; r < 8; ++r) h3[r][j] = fmaxf(acc[r], 0.f);
    }
    __syncthreads();
    if (j < 128) {
        float ga[8], ea[8];
#pragma unroll
        for (int r = 0; r < 8; ++r) { ga[r] = 0.f; ea[r] = 0.f; }
        if (j < 100) {
            for (int d = 0; d < 128; ++d) {
                float w = U1[d * 100 + j];
#pragma unroll
                for (int r = 0; r < 8; ++r) ga[r] += xs[r][d] * w;
            }
#pragma unroll
            for (int r = 0; r < 8; ++r) ea[r] = c1[j];
            for (int c = 0; c < 64; ++c) {
                float w = U1[(128 + c) * 100 + j];
#pragma unroll
                for (int r = 0; r < 8; ++r) ea[r] += h3[r][c] * w;
            }
        }
#pragma unroll
        for (int r = 0; r < 8; ++r) {
            g_out[(b0 + r) * 128 + j] = ga[r];
            e_out[(b0 + r) * 128 + j] = ea[r];
        }
    }
}

// ---------------- main fused UMNN kernel ----------------
// one block per batch row b; 512 threads = 8 waves; wave w owns a 32x32 output
// tile (2x2 of 16x16 MFMA frags). LDS XOR-swizzle ((row&7)<<4) on all stride-256B
// tiles (G4: otherwise 16-way bank conflict on ds_read_b128).
__device__ __forceinline__ void gemm4(const char* __restrict__ inBuf,
                                      const char* __restrict__ wBuf,
                                      int mt2, int nt2, int l15, int lq,
                                      f32x4 acc[2][2])
{
    bf16x8 afr[2][4], bfr[2][4];
#pragma unroll
    for (int mi = 0; mi < 2; ++mi) {
        int row = mt2 * 32 + mi * 16 + l15;
        const char* base = inBuf + row * 256;
        int sw = (row & 7) << 4;
#pragma unroll
        for (int ks = 0; ks < 4; ++ks)
            afr[mi][ks] = *(const bf16x8*)(base + ((ks * 64 + lq * 16) ^ sw));
    }
#pragma unroll
    for (int ni = 0; ni < 2; ++ni) {
        int n = nt2 * 32 + ni * 16 + l15;
        const char* base = wBuf + n * 256;
        int sw = (n & 7) << 4;
#pragma unroll
        for (int ks = 0; ks < 4; ++ks)
            bfr[ni][ks] = *(const bf16x8*)(base + ((ks * 64 + lq * 16) ^ sw));
    }
#pragma unroll
    for (int mi = 0; mi < 2; ++mi)
#pragma unroll
        for (int ni = 0; ni < 2; ++ni) {
            f32x4 a = {0.f, 0.f, 0.f, 0.f};
#pragma unroll
            for (int ks = 0; ks < 4; ++ks)
                a = __builtin_amdgcn_mfma_f32_16x16x32_bf16(afr[mi][ks], bfr[ni][ks], a, 0, 0, 0);
            acc[mi][ni] = a;
        }
}

__global__ __launch_bounds__(512, 1) void umnn_main(
    const float* __restrict__ x,
    const float* __restrict__ ws_g, const float* __restrict__ ws_e,
    const unsigned char* __restrict__ ws, float* __restrict__ out)
{
    extern __shared__ char sm[];
    const int tid = threadIdx.x;
    const int lane = tid & 63, wid = tid >> 6;
    const int l15 = lane & 15, lq = lane >> 4;
    const int b = blockIdx.x;

    // ---- stage weights into LDS (swizzled), plus small vectors
    {
        const uint4* src = (const uint4*)(ws + WT_OFF);   // 6144 x 16B
        for (int ci = tid; ci < 6144; ci += 512) {
            int m = ci >> 11;
            int wi = ci & 2047;
            int n = wi >> 4;
            int part = wi & 15;
            uint4 v = src[ci];
            *(uint4*)(sm + OFF_W + m * 32768 + n * 256 + ((part * 16) ^ ((n & 7) << 4))) = v;
        }
        const float* cb = (const float*)(ws + CB_OFF);
        if (tid < 128) {
            ((float*)(sm + OFF_C2))[tid] = cb[tid];
            ((float*)(sm + OFF_C3))[tid] = cb[128 + tid];
            ((float*)(sm + OFF_C4))[tid] = cb[256 + tid];
            ((float*)(sm + OFF_X))[tid] = x[b * 128 + tid];
            ((float*)(sm + OFF_G))[tid] = ws_g[b * 128 + tid];
            ((float*)(sm + OFF_E))[tid] = ws_e[b * 128 + tid];
        }
    }
    __syncthreads();

    const float* sX  = (const float*)(sm + OFF_X);
    const float* sG  = (const float*)(sm + OFF_G);
    const float* sE  = (const float*)(sm + OFF_E);
    const float* sC2 = (const float*)(sm + OFF_C2);
    const float* sC3 = (const float*)(sm + OFF_C3);
    const float* sC4 = (const float*)(sm + OFF_C4);
    char* bufA = sm + OFF_A;            // 64 x 128 bf16
    char* bufB = sm + OFF_A + 16384;

    const int mt2 = wid & 1;            // wave's 32-row strip
    const int nt2 = wid >> 1;           // wave's 32-col strip
    float regF = 0.f;

    for (int ch = 0; ch < NCHUNK; ++ch) {
        // ---- a1 = relu(t*g + e) -> bufA (bf16, swizzled). pads give exact 0.
        {
#pragma unroll
            for (int p = 0; p < 8; ++p) {
                int rr = p * 8 + wid;                 // row 0..63
                int k0 = (lane) * 2;                  // col pair
                float tt = ((float)(ch * 64 + rr) + 0.5f) * (1.f / 300.f);
                float v0 = fmaxf(0.f, tt * sG[k0]     + sE[k0]);
                float v1 = fmaxf(0.f, tt * sG[k0 + 1] + sE[k0 + 1]);
                unsigned u = (unsigned)f2bf(v0) | ((unsigned)f2bf(v1) << 16);
                *(unsigned*)(bufA + rr * 256 + ((k0 * 2) ^ ((rr & 7) << 4))) = u;
            }
        }
        __syncthreads();

        // ---- layer 2: bufA -> bufB
        {
            f32x4 acc[2][2];
            gemm4(bufA, (const char*)(sm + OFF_W), mt2, nt2, l15, lq, acc);
#pragma unroll
            for (int mi = 0; mi < 2; ++mi)
#pragma unroll
                for (int ni = 0; ni < 2; ++ni) {
                    int n = nt2 * 32 + ni * 16 + l15;
                    float bs = sC2[n];
#pragma unroll
                    for (int j = 0; j < 4; ++j) {
                        int row = mt2 * 32 + mi * 16 + lq * 4 + j;
                        float v = fmaxf(acc[mi][ni][j] + bs, 0.f);
                        *(unsigned short*)(bufB + row * 256 + ((n * 2) ^ ((row & 7) << 4))) = f2bf(v);
                    }
                }
        }
        __syncthreads();

        // ---- layer 3: bufB -> bufA
        {
            f32x4 acc[2][2];
            gemm4(bufB, (const char*)(sm + OFF_W + 32768), mt2, nt2, l15, lq, acc);
#pragma unroll
            for (int mi = 0; mi < 2; ++mi)
#pragma unroll
                for (int ni = 0; ni < 2; ++ni) {
                    int n = nt2 * 32 + ni * 16 + l15;
                    float bs = sC3[n];
#pragma unroll
                    for (int j = 0; j < 4; ++j) {
                        int row = mt2 * 32 + mi * 16 + lq * 4 + j;
                        float v = fmaxf(acc[mi][ni][j] + bs, 0.f);
                        *(unsigned short*)(bufA + row * 256 + ((n * 2) ^ ((row & 7) << 4))) = f2bf(v);
                    }
                }
        }
        __syncthreads();

        // ---- layer 4 + fused epilogue: f = elu(p)+1 ; partial = f . x ; reduce
        {
            f32x4 acc[2][2];
            gemm4(bufA, (const char*)(sm + OFF_W + 65536), mt2, nt2, l15, lq, acc);
#pragma unroll
            for (int mi = 0; mi < 2; ++mi) {
                float s[4] = {0.f, 0.f, 0.f, 0.f};
#pragma unroll
                for (int ni = 0; ni < 2; ++ni) {
                    int n = nt2 * 32 + ni * 16 + l15;   // = output dim d
                    float bs = sC4[n];
                    float xv = sX[n];
#pragma unroll
                    for (int j = 0; j < 4; ++j) {
                        float p = acc[mi][ni][j] + bs;
                        float f = (p > 0.f) ? (p + 1.f) : __expf(p);   // elu(p)+1
                        s[j] += f * xv;
                    }
                }
#pragma unroll
                for (int off = 1; off <= 8; off <<= 1)
#pragma unroll
                    for (int j = 0; j < 4; ++j) s[j] += __shfl_xor(s[j], off);
                if (l15 == 0) {
#pragma unroll
                    for (int j = 0; j < 4; ++j) {
                        int row = mt2 * 32 + mi * 16 + lq * 4 + j;
                        if (ch * 64 + row < TSTEPS) regF += s[j];
                    }
                }
            }
        }
        __syncthreads();   // protect bufA before next chunk's genA
    }

    if (l15 == 0) ((float*)(sm + OFF_P))[wid * 4 + lq] = regF;
    __syncthreads();
    if (tid == 0) {
        float F = 0.f;
        for (int i = 0; i < 32; ++i) F += ((float*)(sm + OFF_P))[i];
        F *= (1.f / 300.f);
        out[b] = 1.f / (1.f + expf(-F));
    }
}

// ---------------- launch ----------------
extern "C" void kernel_launch(void* const* d_in, const int* in_sizes, int n_in,
                              void* d_out, int out_size, void* d_ws, size_t ws_size,
                              hipStream_t stream)
{
    const float* x  = (const float*)d_in[0];
    const float* W1 = (const float*)d_in[1];
    const float* b1 = (const float*)d_in[2];
    const float* W2 = (const float*)d_in[3];
    const float* b2 = (const float*)d_in[4];
    const float* W3 = (const float*)d_in[5];
    const float* b3 = (const float*)d_in[6];
    const float* U1 = (const float*)d_in[7];
    const float* c1 = (const float*)d_in[8];
    const float* U2 = (const float*)d_in[9];
    const float* c2 = (const float*)d_in[10];
    const float* U3 = (const float*)d_in[11];
    const float* c3 = (const float*)d_in[12];
    const float* U4 = (const float*)d_in[13];
    const float* c4 = (const float*)d_in[14];
    float* out = (float*)d_out;
    unsigned char* ws = (unsigned char*)d_ws;

    prep_kernel<<<48, 256, 0, stream>>>(U2, c2, U3, c3, U4, c4, ws);
    embed_kernel<<<BATCH / 8, 256, 0, stream>>>(x, W1, b1, W2, b2, W3, b3, U1, c1,
                                                (float*)(ws + G_OFF), (float*)(ws + E_OFF));
    hipFuncSetAttribute((const void*)umnn_main,
                        hipFuncAttributeMaxDynamicSharedMemorySize, SMEM_SZ);
    umnn_main<<<BATCH, 512, SMEM_SZ, stream>>>(x, (const float*)(ws + G_OFF),
                                               (const float*)(ws + E_OFF), ws, out);
}

// Round 3
// 168.305 us; speedup vs baseline: 1.7697x; 1.7697x over previous
//
#include <hip/hip_runtime.h>

// ---------------- types / helpers ----------------
typedef __attribute__((ext_vector_type(8))) short bf16x8;   // 8 bf16 = 4 VGPR
typedef __attribute__((ext_vector_type(4))) float f32x4;
typedef __attribute__((ext_vector_type(16))) float f32x16;
typedef int v2i __attribute__((ext_vector_type(2)));

union U4B { unsigned u[4]; bf16x8 v; };

__device__ __forceinline__ unsigned short f2bf(float f) {
    union { float f; unsigned u; } v; v.f = f;
    unsigned r = v.u + 0x7fffu + ((v.u >> 16) & 1u);   // RNE
    return (unsigned short)(r >> 16);
}

__device__ __forceinline__ unsigned pkbf(float a, float b) {
    unsigned r;
    asm("v_cvt_pk_bf16_f32 %0, %1, %2" : "=v"(r) : "v"(a), "v"(b));
    return r;
}

__device__ __forceinline__ f32x16 zero16() {
    f32x16 v;
#pragma unroll
    for (int i = 0; i < 16; ++i) v[i] = 0.f;
    return v;
}

// ---------------- problem constants ----------------
#define BATCH   2048
#define TSTEPS  300
#define ROWS_PB 4            // batch rows per main block
// workspace layout (bytes)
#define WT_OFF  0            // 3 * 128*128 bf16 = 98304 (W2',W3',W4' padded, bias@k=100)
#define G_OFF   98304        // 2048*128 f32
#define E_OFF   1146880      // 2048*128 f32
// main-kernel LDS (bytes)
#define OFF_X   98304        // 4*128 f32
#define OFF_G   100352
#define OFF_E   102400
#define OFF_P   104448       // 8 f32 wave partials
#define SMEM_SZ 104480

// ---------------- prep: pack/pad weights to bf16, fold biases in ----------------
// Layout per matrix m: [n][k] rows of 256B. Bias lives at k==100; act[100]==1 is
// propagated through layers via identity rows n==100 in W2'/W3'.
__global__ __launch_bounds__(256) void prep_kernel(
    const float* __restrict__ U2, const float* __restrict__ c2,
    const float* __restrict__ U3, const float* __restrict__ c3,
    const float* __restrict__ U4, const float* __restrict__ c4,
    unsigned char* __restrict__ ws)
{
    int idx = blockIdx.x * 256 + threadIdx.x;          // grid = 48 blocks
    for (int i = idx; i < 3 * 128 * 128; i += 48 * 256) {
        int m = i >> 14;
        int r = i & 16383;
        int n = r >> 7;           // out-neuron (row)
        int k = r & 127;          // in-neuron
        float v = 0.f;
        if (m == 2) {             // U4: (k=100 in) x (n=128 out)
            if (k < 100)       v = U4[k * 128 + n];
            else if (k == 100) v = c4[n];
        } else {                  // U2 / U3: 100x100
            const float* U = (m == 0) ? U2 : U3;
            const float* c = (m == 0) ? c2 : c3;
            if (n < 100) {
                if (k < 100)       v = U[k * 100 + n];
                else if (k == 100) v = c[n];
            } else if (n == 100 && k == 100) {
                v = 1.f;          // identity pass-through of the bias-carrier 1
            }
        }
        *(unsigned short*)(ws + WT_OFF + m * 32768 + n * 256 + k * 2) = f2bf(v);
    }
}

// ---------------- embedding net + per-row g,e precompute ----------------
// g = x @ U1[0:128,:],  e = h @ U1[128:192,:] + c1 ; e[100]=1 (bias carrier).
__global__ __launch_bounds__(256) void embed_kernel(
    const float* __restrict__ x,
    const float* __restrict__ W1, const float* __restrict__ b1,
    const float* __restrict__ W2, const float* __restrict__ b2,
    const float* __restrict__ W3, const float* __restrict__ b3,
    const float* __restrict__ U1, const float* __restrict__ c1,
    float* __restrict__ g_out, float* __restrict__ e_out)
{
    __shared__ float xs[4][128];
    __shared__ float h1[4][200];
    __shared__ float h2[4][200];
    __shared__ float h3[4][64];
    const int tid = threadIdx.x;
    const int b0 = blockIdx.x * 4;   // grid = 512 blocks

    for (int i = tid; i < 4 * 128; i += 256) {
        int r = i >> 7, d = i & 127;
        xs[r][d] = x[(b0 + r) * 128 + d];
    }
    __syncthreads();

    const int j = tid;
    if (j < 200) {
        float acc[4];
#pragma unroll
        for (int r = 0; r < 4; ++r) acc[r] = b1[j];
        for (int d = 0; d < 128; ++d) {
            float w = W1[d * 200 + j];
#pragma unroll
            for (int r = 0; r < 4; ++r) acc[r] += xs[r][d] * w;
        }
#pragma unroll
        for (int r = 0; r < 4; ++r) h1[r][j] = fmaxf(acc[r], 0.f);
    }
    __syncthreads();
    if (j < 200) {
        float acc[4];
#pragma unroll
        for (int r = 0; r < 4; ++r) acc[r] = b2[j];
        for (int d = 0; d < 200; ++d) {
            float w = W2[d * 200 + j];
#pragma unroll
            for (int r = 0; r < 4; ++r) acc[r] += h1[r][d] * w;
        }
#pragma unroll
        for (int r = 0; r < 4; ++r) h2[r][j] = fmaxf(acc[r], 0.f);
    }
    __syncthreads();
    if (j < 64) {
        float acc[4];
#pragma unroll
        for (int r = 0; r < 4; ++r) acc[r] = b3[j];
        for (int d = 0; d < 200; ++d) {
            float w = W3[d * 64 + j];
#pragma unroll
            for (int r = 0; r < 4; ++r) acc[r] += h2[r][d] * w;
        }
#pragma unroll
        for (int r = 0; r < 4; ++r) h3[r][j] = fmaxf(acc[r], 0.f);
    }
    __syncthreads();
    if (j < 128) {
        float ga[4], ea[4];
#pragma unroll
        for (int r = 0; r < 4; ++r) { ga[r] = 0.f; ea[r] = 0.f; }
        if (j < 100) {
            for (int d = 0; d < 128; ++d) {
                float w = U1[d * 100 + j];
#pragma unroll
                for (int r = 0; r < 4; ++r) ga[r] += xs[r][d] * w;
            }
#pragma unroll
            for (int r = 0; r < 4; ++r) ea[r] = c1[j];
            for (int c = 0; c < 64; ++c) {
                float w = U1[(128 + c) * 100 + j];
#pragma unroll
                for (int r = 0; r < 4; ++r) ea[r] += h3[r][c] * w;
            }
        } else if (j == 100) {
#pragma unroll
            for (int r = 0; r < 4; ++r) ea[r] = 1.f;   // bias carrier
        }
#pragma unroll
        for (int r = 0; r < 4; ++r) {
            g_out[(b0 + r) * 128 + j] = ga[r];
            e_out[(b0 + r) * 128 + j] = ea[r];
        }
    }
}

// ---------------- main fused UMNN kernel (barrier-free per-wave pipelines) ----
// Block = 4 batch rows x 8 waves (512 thr). Wave = (row = wid>>1, half = wid&1);
// 5 tiles of 32 t-cols each. Acts live in registers as 32x32x16 B-frags
// (col = t = lane&31, k = 16ks + 8*(lane>>5) + j). Weights = A-frags from
// swizzled LDS (row n = 32f + lane&31). C: col=lane&31, row=(r&3)+8(r>>2)+4hi.
// Layer transition: relu + cvt_pk_bf16 + permlane32_swap (in-register transpose).
__global__ __launch_bounds__(512, 1) void umnn_main(
    const float* __restrict__ x,
    const float* __restrict__ ws_g, const float* __restrict__ ws_e,
    const unsigned char* __restrict__ ws, float* __restrict__ out)
{
    extern __shared__ char sm[];
    float* sX = (float*)(sm + OFF_X);   // [4][128]
    float* sG = (float*)(sm + OFF_G);
    float* sE = (float*)(sm + OFF_E);
    float* sP = (float*)(sm + OFF_P);
    const int tid = threadIdx.x;
    const int lane = tid & 63, wid = tid >> 6;
    const int l31 = lane & 31, hi = lane >> 5;
    const int b4 = blockIdx.x * ROWS_PB;

    // ---- stage weights (swizzled) + per-row vectors
    {
        const uint4* src = (const uint4*)(ws + WT_OFF);   // 6144 x 16B
        for (int ci = tid; ci < 6144; ci += 512) {
            int m = ci >> 11, wi = ci & 2047, n = wi >> 4, part = wi & 15;
            uint4 v = src[ci];
            *(uint4*)(sm + m * 32768 + n * 256 + ((part * 16) ^ ((n & 7) << 4))) = v;
        }
        {
            int i = tid;   // 512 elements each, one per thread
            int r = i >> 7, d = i & 127;
            sX[i] = x[(b4 + r) * 128 + d];
            sG[i] = ws_g[(b4 + r) * 128 + d];
            sE[i] = ws_e[(b4 + r) * 128 + d];
        }
    }
    __syncthreads();

    const int row = wid >> 1, half = wid & 1;
    const float* gR = sG + row * 128;
    const float* eR = sE + row * 128;
    const float* xR = sX + row * 128;
    const int sw = (l31 & 7) << 4;                 // weight-read swizzle
    const char* wB2 = sm;
    const char* wB3 = sm + 32768;
    const char* wB4 = sm + 65536;

    float sumF = 0.f;

#pragma unroll 1
    for (int s = 0; s < 5; ++s) {
        const int t = half * 160 + s * 32 + l31;
        const float tt = ((float)t + 0.5f) * (1.f / 300.f);

        // ---- genA: B[ks] = bf16(relu(tt*g + e)), ks 0..6 (k 112..127 all zero)
        bf16x8 B[7];
#pragma unroll
        for (int ks = 0; ks < 7; ++ks) {
            const int k0 = ks * 16 + hi * 8;
            f32x4 g0 = *(const f32x4*)(gR + k0);
            f32x4 g1 = *(const f32x4*)(gR + k0 + 4);
            f32x4 e0 = *(const f32x4*)(eR + k0);
            f32x4 e1 = *(const f32x4*)(eR + k0 + 4);
            float a0 = fmaxf(fmaf(tt, g0[0], e0[0]), 0.f);
            float a1 = fmaxf(fmaf(tt, g0[1], e0[1]), 0.f);
            float a2 = fmaxf(fmaf(tt, g0[2], e0[2]), 0.f);
            float a3 = fmaxf(fmaf(tt, g0[3], e0[3]), 0.f);
            float a4 = fmaxf(fmaf(tt, g1[0], e1[0]), 0.f);
            float a5 = fmaxf(fmaf(tt, g1[1], e1[1]), 0.f);
            float a6 = fmaxf(fmaf(tt, g1[2], e1[2]), 0.f);
            float a7 = fmaxf(fmaf(tt, g1[3], e1[3]), 0.f);
            U4B u;
            u.u[0] = pkbf(a0, a1); u.u[1] = pkbf(a2, a3);
            u.u[2] = pkbf(a4, a5); u.u[3] = pkbf(a6, a7);
            B[ks] = u.v;
        }

        // ---- layers 2 and 3: GEMM + relu + in-register repack
#pragma unroll
        for (int L = 0; L < 2; ++L) {
            const char* wb = (L == 0) ? wB2 : wB3;
            f32x16 acc[4];
#pragma unroll
            for (int f = 0; f < 4; ++f) acc[f] = zero16();
#pragma unroll
            for (int ks = 0; ks < 7; ++ks) {
                const int ko = ks * 32 + hi * 16;
#pragma unroll
                for (int f = 0; f < 4; ++f) {
                    bf16x8 a = *(const bf16x8*)(wb + (32 * f + l31) * 256 + (ko ^ sw));
                    acc[f] = __builtin_amdgcn_mfma_f32_32x32x16_bf16(a, B[ks], acc[f], 0, 0, 0);
                }
            }
            // repack: C(frag f) -> B[2f] (+ B[2f+1] for f<3); relu fused
#pragma unroll
            for (int f = 0; f < 4; ++f) {
#pragma unroll
                for (int r = 0; r < 16; ++r) acc[f][r] = fmaxf(acc[f][r], 0.f);
                {   // e=0 half: C regs 0..7 -> B[2f]
                    unsigned u  = pkbf(acc[f][0], acc[f][1]);
                    unsigned u2 = pkbf(acc[f][2], acc[f][3]);
                    unsigned v  = pkbf(acc[f][4], acc[f][5]);
                    unsigned v2 = pkbf(acc[f][6], acc[f][7]);
                    v2i r1 = __builtin_amdgcn_permlane32_swap(u, v, false, false);
                    v2i r2 = __builtin_amdgcn_permlane32_swap(u2, v2, false, false);
                    U4B b; b.u[0] = r1.x; b.u[1] = r2.x; b.u[2] = r1.y; b.u[3] = r2.y;
                    B[2 * f] = b.v;
                }
                if (f < 3) {   // e=1 half: C regs 8..15 -> B[2f+1]
                    unsigned u  = pkbf(acc[f][8],  acc[f][9]);
                    unsigned u2 = pkbf(acc[f][10], acc[f][11]);
                    unsigned v  = pkbf(acc[f][12], acc[f][13]);
                    unsigned v2 = pkbf(acc[f][14], acc[f][15]);
                    v2i r1 = __builtin_amdgcn_permlane32_swap(u, v, false, false);
                    v2i r2 = __builtin_amdgcn_permlane32_swap(u2, v2, false, false);
                    U4B b; b.u[0] = r1.x; b.u[1] = r2.x; b.u[2] = r1.y; b.u[3] = r2.y;
                    B[2 * f + 1] = b.v;
                }
            }
        }

        // ---- layer 4 + fused elu(p)+1 dot x
        float sdot = 0.f;
#pragma unroll
        for (int f = 0; f < 4; ++f) {
            f32x16 acc = zero16();
#pragma unroll
            for (int ks = 0; ks < 7; ++ks) {
                const int ko = ks * 32 + hi * 16;
                bf16x8 a = *(const bf16x8*)(wB4 + (32 * f + l31) * 256 + (ko ^ sw));
                acc = __builtin_amdgcn_mfma_f32_32x32x16_bf16(a, B[ks], acc, 0, 0, 0);
            }
#pragma unroll
            for (int q = 0; q < 4; ++q) {
                const int n0 = f * 32 + q * 8 + hi * 4;   // 4 consecutive d's
                f32x4 xv = *(const f32x4*)(xR + n0);
#pragma unroll
                for (int i = 0; i < 4; ++i) {
                    float p = acc[q * 4 + i];
                    float fv = (p > 0.f) ? (p + 1.f) : __expf(p);   // elu+1
                    sdot = fmaf(fv, xv[i], sdot);
                }
            }
        }
        if (t < TSTEPS) sumF += sdot;
    }

    // ---- reduce: wave -> block pairs -> sigmoid
#pragma unroll
    for (int off = 32; off >= 1; off >>= 1) sumF += __shfl_xor(sumF, off);
    if (lane == 0) sP[wid] = sumF;
    __syncthreads();
    if (tid < ROWS_PB) {
        float F = (sP[tid * 2] + sP[tid * 2 + 1]) * (1.f / 300.f);
        out[b4 + tid] = 1.f / (1.f + __expf(-F));
    }
}

// ---------------- launch ----------------
extern "C" void kernel_launch(void* const* d_in, const int* in_sizes, int n_in,
                              void* d_out, int out_size, void* d_ws, size_t ws_size,
                              hipStream_t stream)
{
    const float* x  = (const float*)d_in[0];
    const float* W1 = (const float*)d_in[1];
    const float* b1 = (const float*)d_in[2];
    const float* W2 = (const float*)d_in[3];
    const float* b2 = (const float*)d_in[4];
    const float* W3 = (const float*)d_in[5];
    const float* b3 = (const float*)d_in[6];
    const float* U1 = (const float*)d_in[7];
    const float* c1 = (const float*)d_in[8];
    const float* U2 = (const float*)d_in[9];
    const float* c2 = (const float*)d_in[10];
    const float* U3 = (const float*)d_in[11];
    const float* c3 = (const float*)d_in[12];
    const float* U4 = (const float*)d_in[13];
    const float* c4 = (const float*)d_in[14];
    float* out = (float*)d_out;
    unsigned char* ws = (unsigned char*)d_ws;

    prep_kernel<<<48, 256, 0, stream>>>(U2, c2, U3, c3, U4, c4, ws);
    embed_kernel<<<BATCH / 4, 256, 0, stream>>>(x, W1, b1, W2, b2, W3, b3, U1, c1,
                                                (float*)(ws + G_OFF), (float*)(ws + E_OFF));
    hipFuncSetAttribute((const void*)umnn_main,
                        hipFuncAttributeMaxDynamicSharedMemorySize, SMEM_SZ);
    umnn_main<<<BATCH / ROWS_PB, 512, SMEM_SZ, stream>>>(
        x, (const float*)(ws + G_OFF), (const float*)(ws + E_OFF), ws, out);
}